// Round 3
// baseline (557.545 us; speedup 1.0000x reference)
//
#include <hip/hip_runtime.h>
#include <cstdint>
#include <cstddef>

// ============================================================================
// VQ-VAE encode: conv3x3(SAME) -> linear (folded) -> argmin over 8192 codes.
//
// Round 13: screen9b = R12's counted-vmcnt pipeline, hardened.
//   R12 container failed (no counters). Deltas vs known-running screen8
//   minimized: LDS back to 96 KB (screen8-proven; esq via global loads in
//   epilogue, screen8-proven), barriers via __builtin_amdgcn_s_barrier(),
//   counted s_waitcnt vmcnt(N) as standalone asm. Pipeline per m201/m218
//   (T3/T4): chunk gi+2 staged at step gi; vmcnt(4) leaves its 4 loads in
//   flight across both barriers and the whole next MFMA phase. Argmin
//   epilogue moved AFTER the publish barrier so its VALU/stores overlap the
//   prefetch flight. Tail steps drain vmcnt(0).
//   Numerics bit-identical to screen7/8 (same fragments, same kt order).
//   convm6_k: tap-amplification-free conv (unchanged).
//   refine3_k: exact fp32 re-score of candidates within 0.25 of screen min.
// argmin tie-break everywhere: strict < with smaller-index preference.
// ============================================================================

#define CIN_  512
#define E_    4608
#define M_    16384

typedef _Float16 half4_t __attribute__((ext_vector_type(4)));
typedef _Float16 half8_t __attribute__((ext_vector_type(8)));
typedef float f32x4 __attribute__((ext_vector_type(4)));

#define GLOAD_LDS16(gptr, lptr)                                         \
    __builtin_amdgcn_global_load_lds(                                   \
        (const __attribute__((address_space(1))) unsigned int*)(gptr),  \
        (__attribute__((address_space(3))) unsigned int*)(lptr), 16, 0, 0)

// ---------------- transpose ----------------
__global__ void tkern(const float* __restrict__ src, float* __restrict__ dst,
                      int R, int C) {
    __shared__ float t[32][33];
    int c = blockIdx.x * 32 + threadIdx.x;
    int r = blockIdx.y * 32 + threadIdx.y;
    if (r < R && c < C) t[threadIdx.y][threadIdx.x] = src[(size_t)r * C + c];
    __syncthreads();
    int rr = blockIdx.x * 32 + threadIdx.y;
    int cc = blockIdx.y * 32 + threadIdx.x;
    if (rr < C && cc < R) dst[(size_t)rr * R + cc] = t[threadIdx.x][threadIdx.y];
}

// ---------------- fold: W2x[plane][tap][d][512c] fp16 hi/lo ----------------
__global__ __launch_bounds__(256) void fold5_k(const float* __restrict__ conv_w,
                                               const float* __restrict__ lwT,
                                               _Float16* __restrict__ W2x) {
    int e0 = blockIdx.x * 8;
    int d = threadIdx.x;
    float acc[8];
    #pragma unroll
    for (int j = 0; j < 8; ++j) acc[j] = 0.f;
    for (int co = 0; co < 256; ++co) {
        float lw = lwT[co * 256 + d];
        const float* cwr = conv_w + (size_t)co * E_ + e0;   // wave-uniform
        #pragma unroll
        for (int j = 0; j < 8; ++j) acc[j] += cwr[j] * lw;
    }
    #pragma unroll
    for (int j = 0; j < 8; ++j) {
        int e = e0 + j;
        int c = e / 9, t9 = e - c * 9;
        _Float16 h = (_Float16)acc[j];
        _Float16 l = (_Float16)(acc[j] - (float)h);
        W2x[((size_t)(t9 * 256 + d)) * 512 + c] = h;
        W2x[((size_t)((9 + t9) * 256 + d)) * 512 + c] = l;
    }
}

__global__ void bias_k(const float* __restrict__ lwT, const float* __restrict__ conv_b,
                       const float* __restrict__ lin_b, float* __restrict__ b2) {
    int d = threadIdx.x;
    float acc = lin_b[d];
    for (int co = 0; co < 256; ++co) acc += lwT[co * 256 + d] * conv_b[co];
    b2[d] = acc;
}

// ---------------- latent -> channel-last fp16 hi/lo planes ----------------
__global__ __launch_bounds__(256) void packlat_k(const float* __restrict__ lat,
                                                 _Float16* __restrict__ Xnp) {
    int b = blockIdx.x, t = threadIdx.x;
    __shared__ float lt[128][65];
    const float* src = lat + (size_t)b * 512 * 64;
    _Float16* dst = Xnp + (size_t)b * 64 * 1024;
    for (int c0 = 0; c0 < 512; c0 += 128) {
        __syncthreads();
        #pragma unroll
        for (int j = 0; j < 8; ++j) {
            int f4 = t + j * 256;
            int cc = f4 >> 4, p4 = (f4 & 15) * 4;
            float4 v = *(const float4*)(src + (size_t)(c0 + cc) * 64 + p4);
            lt[cc][p4] = v.x; lt[cc][p4 + 1] = v.y;
            lt[cc][p4 + 2] = v.z; lt[cc][p4 + 3] = v.w;
        }
        __syncthreads();
        int pix = t >> 2, cr = (t & 3) * 32;
        #pragma unroll
        for (int q = 0; q < 4; ++q) {
            half8_t hh, ll;
            #pragma unroll
            for (int j = 0; j < 8; ++j) {
                float v = lt[cr + q * 8 + j][pix];
                _Float16 h = (_Float16)v;
                hh[j] = h; ll[j] = (_Float16)(v - (float)h);
            }
            *(half8_t*)(dst + (size_t)pix * 1024 + c0 + cr + q * 8) = hh;
            *(half8_t*)(dst + (size_t)pix * 1024 + 512 + c0 + cr + q * 8) = ll;
        }
    }
}

// ---------------- conv MFMA v6: in-LDS tap shifts, A staged once per chunk --
// grid (128 m-tiles, 2 n-halves), 256 thr = 4 waves (2x2 of 64x64).
// LDS 64 KB static: A dbuf 2 x {Ah 8K, Al 8K} + B dbuf 2 x {Bh 8K, Bl 8K}.
__global__ __launch_bounds__(256) void convm6_k(
    const _Float16* __restrict__ Xnp, const _Float16* __restrict__ W2x,
    const float* __restrict__ b2, float* __restrict__ yb) {
    __shared__ char sm[65536];
    int m0 = blockIdx.x * 128, n0 = blockIdx.y * 128;
    int tid = threadIdx.x, w = tid >> 6, lane = tid & 63;
    int wm = w & 1, wn = w >> 1;
    int fr = lane & 15, fq = lane >> 4;

    // B fragment-read offsets (convm4-verified slot-permute)
    int xq = (fq ^ ((fr >> 1) & 3)) << 4;
    int boff[4];
    #pragma unroll
    for (int i = 0; i < 4; ++i) boff[i] = (wn * 64 + i * 16 + fr) * 64 + xq;
    // A fragment row geometry: rr = wm*64 + s*16 + fr -> (imgbit, ph, pw)
    int imgoff[4], ph[4], pw[4];
    #pragma unroll
    for (int s = 0; s < 4; ++s) {
        int rr = wm * 64 + s * 16 + fr;
        imgoff[s] = rr & 64; ph[s] = (rr >> 3) & 7; pw[s] = rr & 7;
    }
    // staging slot geometry (2 granules per thread per 8 KB tile)
    int slt[2], sr[2], sq[2];
    #pragma unroll
    for (int i = 0; i < 2; ++i) {
        int s = w * 128 + i * 64 + lane;
        slt[i] = s;
        sr[i] = s >> 2;
        sq[i] = ((s & 3) ^ ((s >> 3) & 3)) * 8;
    }

    auto stageA = [&](int cc, int buf) {
        char* L = sm + buf * 16384;
        #pragma unroll
        for (int i = 0; i < 2; ++i) {
            const _Float16* base =
                Xnp + (size_t)(m0 + sr[i]) * 1024 + cc * 32 + sq[i];
            GLOAD_LDS16(base, L + slt[i] * 16);              // hi plane
            GLOAD_LDS16(base + 512, L + 8192 + slt[i] * 16); // lo plane
        }
    };
    auto stageB = [&](int tap, int cc, int buf) {
        char* L = sm + 32768 + buf * 16384;
        #pragma unroll
        for (int i = 0; i < 2; ++i) {
            const _Float16* bb =
                W2x + ((size_t)(tap * 256 + n0 + sr[i])) * 512 + cc * 32 + sq[i];
            GLOAD_LDS16(bb, L + slt[i] * 16);
            GLOAD_LDS16(bb + (size_t)9 * 256 * 512, L + 8192 + slt[i] * 16);
        }
    };

    f32x4 acc[4][4];
    #pragma unroll
    for (int s = 0; s < 4; ++s)
        #pragma unroll
        for (int t = 0; t < 4; ++t)
            #pragma unroll
            for (int r = 0; r < 4; ++r) acc[s][t][r] = 0.f;

    stageA(0, 0);
    stageB(0, 0, 0);
    const half8_t zfrag = {};
    int gi = 0;
    for (int cc = 0; cc < 16; ++cc) {
        const char* Ab = sm + (cc & 1) * 16384;
        for (int tap = 0; tap < 9; ++tap, ++gi) {
            __syncthreads();
            if (tap < 8) stageB(tap + 1, cc, (gi + 1) & 1);
            else if (cc < 15) stageB(0, cc + 1, (gi + 1) & 1);
            if (tap == 7 && cc < 15) stageA(cc + 1, (cc + 1) & 1);

            int dy = tap / 3 - 1, dx = tap - (tap / 3) * 3 - 1;
            // A fragments: shifted pixels, invalid -> zero
            half8_t ah[4], al[4];
            #pragma unroll
            for (int s = 0; s < 4; ++s) {
                int ih = ph[s] + dy, iw = pw[s] + dx;
                bool v = ((unsigned)ih < 8u) && ((unsigned)iw < 8u);
                int pp = imgoff[s] + (v ? ih * 8 + iw : 0);
                int ao = pp * 64 + ((fq ^ ((pp >> 1) & 3)) << 4);
                half8_t a0 = *(const half8_t*)(Ab + ao);
                half8_t a1 = *(const half8_t*)(Ab + 8192 + ao);
                ah[s] = v ? a0 : zfrag;
                al[s] = v ? a1 : zfrag;
            }
            const char* Bb = sm + 32768 + (gi & 1) * 16384;
            half8_t bh[4], bl[4];
            #pragma unroll
            for (int t = 0; t < 4; ++t) {
                bh[t] = *(const half8_t*)(Bb + boff[t]);
                bl[t] = *(const half8_t*)(Bb + 8192 + boff[t]);
            }
            #pragma unroll
            for (int s = 0; s < 4; ++s)
                #pragma unroll
                for (int t = 0; t < 4; ++t)
                    acc[s][t] = __builtin_amdgcn_mfma_f32_16x16x32_f16(
                        ah[s], bh[t], acc[s][t], 0, 0, 0);
            #pragma unroll
            for (int s = 0; s < 4; ++s)
                #pragma unroll
                for (int t = 0; t < 4; ++t)
                    acc[s][t] = __builtin_amdgcn_mfma_f32_16x16x32_f16(
                        ah[s], bl[t], acc[s][t], 0, 0, 0);
            #pragma unroll
            for (int s = 0; s < 4; ++s)
                #pragma unroll
                for (int t = 0; t < 4; ++t)
                    acc[s][t] = __builtin_amdgcn_mfma_f32_16x16x32_f16(
                        al[s], bh[t], acc[s][t], 0, 0, 0);
        }
    }

    // epilogue: +bias, write yb fp32 only
    float bv[4];
    #pragma unroll
    for (int t = 0; t < 4; ++t) bv[t] = b2[n0 + wn * 64 + t * 16 + fr];
    #pragma unroll
    for (int s = 0; s < 4; ++s)
        #pragma unroll
        for (int r = 0; r < 4; ++r) {
            int m = m0 + wm * 64 + s * 16 + fq * 4 + r;
            #pragma unroll
            for (int t = 0; t < 4; ++t) {
                int d = n0 + wn * 64 + t * 16 + fr;
                yb[(size_t)m * 256 + d] = acc[s][t][r] + bv[t];
            }
        }
}

// ---------------- fused post-conv pack: A2<-yb, B2<-emb, esq<-emb ----------
// 512 blocks x 256 thr. Runs AFTER convm6 (Xnp dead -> A2/B2 regions free).
__global__ __launch_bounds__(256) void pack2_k(
    const float* __restrict__ yb, const float* __restrict__ emb,
    _Float16* __restrict__ A2, _Float16* __restrict__ B2,
    float* __restrict__ esq) {
    // A2 <- yb : 16384 rows x 256 = 1,048,576 float4 groups
    #pragma unroll
    for (int it = 0; it < 8; ++it) {
        int i = (blockIdx.x + it * 512) * 256 + threadIdx.x;
        float4 v = *(const float4*)(yb + (size_t)i * 4);
        half4_t h = {(_Float16)v.x, (_Float16)v.y, (_Float16)v.z, (_Float16)v.w};
        *(half4_t*)(A2 + (size_t)i * 4) = h;
    }
    // B2 + esq <- emb : 8192 rows
    int w = threadIdx.x >> 6, lane = threadIdx.x & 63;
    #pragma unroll
    for (int j = 0; j < 4; ++j) {
        int k = blockIdx.x * 16 + w * 4 + j;
        float4 v = *(const float4*)(emb + (size_t)k * 256 + lane * 4);
        half4_t h = {(_Float16)v.x, (_Float16)v.y, (_Float16)v.z, (_Float16)v.w};
        *(half4_t*)(B2 + (size_t)k * 256 + lane * 4) = h;
        float s = v.x * v.x + v.y * v.y + v.z * v.z + v.w * v.w;
        #pragma unroll
        for (int m = 32; m >= 1; m >>= 1) s += __shfl_xor(s, m, 64);
        if (lane == 0) esq[k] = s;
    }
}

// ---------------- MFMA screen v9b: A-stationary + counted-vmcnt pipeline ---
// grid 256 (one block per 64-row m-tile), 512 thr = 8 waves. Wave w owns
// codes [nt*512 + w*64, +64). LDS 96 KB (screen8-proven size): A 32K (8
// kt-chunks) | B dbuf 2x32K. 128 chunks (gi = nt*8+kt); chunk gi+2 staged at
// step gi; counted vmcnt(4) leaves its loads in flight across both barriers
// and the next MFMA phase. Tail drains vmcnt(0). Argmin epilogue (esq global
// loads, screen8-proven) placed AFTER the publish barrier to overlap the
// prefetch flight. Scores bitwise identical to screen7/8.
__global__ __launch_bounds__(512) void screen9_k(
    const _Float16* __restrict__ A2, const _Float16* __restrict__ B2,
    const float* __restrict__ esq, float* __restrict__ ps2, int* __restrict__ pi2) {
    __shared__ char sm[98304];   // A 32K | B0 32K | B1 32K
    int m0 = blockIdx.x * 64;
    int tid = threadIdx.x, w = tid >> 6, lane = tid & 63;
    int fr = lane & 15, fq = lane >> 4;
    int xq = (fq ^ ((fr >> 1) & 3)) << 4;

    // fragment-read offsets (both-sides slot-permute; proven conflict-free)
    int aoff[4], boff[4];
    #pragma unroll
    for (int i = 0; i < 4; ++i) {
        aoff[i] = (i * 16 + fr) * 64 + xq;             // + kt*4096
        boff[i] = (w * 64 + i * 16 + fr) * 64 + xq;    // within B buffer
    }

    // staging granule geometry: 4 granules/thread per 32 KB region.
    int gA_row[4], gA_ch[4], gB_row[4], gSq[4];
    #pragma unroll
    for (int i = 0; i < 4; ++i) {
        int g = i * 512 + tid;
        gA_row[i] = (g >> 2) & 63;
        gA_ch[i]  = g >> 8;
        gB_row[i] = g >> 2;
        gSq[i]    = ((g & 3) ^ ((g >> 3) & 3)) * 8;
    }

    auto stageB = [&](int c, int buf) {   // chunk c: nt = c>>3, kt = c&7
        char* L = sm + 32768 + buf * 32768;
        int n0 = (c >> 3) * 512, ko = (c & 7) * 32;
        #pragma unroll
        for (int i = 0; i < 4; ++i) {
            int g = i * 512 + tid;
            GLOAD_LDS16(B2 + (size_t)(n0 + gB_row[i]) * 256 + ko + gSq[i],
                        L + g * 16);
        }
    };

    // ---- prologue: A (4 loads), B chunk0 (4), B chunk1 (4) ----
    #pragma unroll
    for (int i = 0; i < 4; ++i) {
        int g = i * 512 + tid;
        GLOAD_LDS16(A2 + (size_t)(m0 + gA_row[i]) * 256 + gA_ch[i] * 32 + gSq[i],
                    sm + g * 16);
    }
    stageB(0, 0);
    stageB(1, 1);
    // A + chunk0 complete (chunk1's 4 newest stay in flight), publish
    asm volatile("s_waitcnt vmcnt(4)" ::: "memory");
    __builtin_amdgcn_s_barrier();

    f32x4 acc[4][4];
    #pragma unroll
    for (int s = 0; s < 4; ++s)
        #pragma unroll
        for (int t = 0; t < 4; ++t)
            #pragma unroll
            for (int r = 0; r < 4; ++r) acc[s][t][r] = 0.f;

    for (int gi = 0; gi < 128; ++gi) {
        int kt = gi & 7, nt = gi >> 3;
        const char* Ab = sm + kt * 4096;
        const char* Bb = sm + 32768 + (gi & 1) * 32768;
        half8_t af[4], bf[4];
        #pragma unroll
        for (int s = 0; s < 4; ++s) af[s] = *(const half8_t*)(Ab + aoff[s]);
        #pragma unroll
        for (int t = 0; t < 4; ++t) bf[t] = *(const half8_t*)(Bb + boff[t]);
        __builtin_amdgcn_s_setprio(1);
        #pragma unroll
        for (int s = 0; s < 4; ++s)
            #pragma unroll
            for (int t = 0; t < 4; ++t)
                acc[s][t] = __builtin_amdgcn_mfma_f32_16x16x32_f16(
                    af[s], bf[t], acc[s][t], 0, 0, 0);
        __builtin_amdgcn_s_setprio(0);

        // all waves finished READING buf[gi&1] (frags consumed into regs)
        __builtin_amdgcn_s_barrier();
        if (gi + 2 < 128) {
            stageB(gi + 2, gi & 1);   // overwrite the buffer just released
            // chunk gi+1 (oldest 4 + any epilogue mem ops) drained;
            // chunk gi+2's 4 loads stay in flight
            asm volatile("s_waitcnt vmcnt(4)" ::: "memory");
        } else {
            // tail: nothing staged -> drain fully so chunk gi+1 is visible
            asm volatile("s_waitcnt vmcnt(0)" ::: "memory");
        }
        __builtin_amdgcn_s_barrier();

        if (kt == 7) {
            // per-n-tile argmin epilogue AFTER publish: VALU + stores overlap
            // the in-flight prefetch. Register + esq/ps2/pi2 global only.
            int n0 = nt * 512;
            float esv[4];
            #pragma unroll
            for (int t = 0; t < 4; ++t) esv[t] = esq[n0 + w * 64 + t * 16 + fr];
            int colIdx = nt * 8 + w;
            #pragma unroll
            for (int s = 0; s < 4; ++s) {
                #pragma unroll
                for (int r = 0; r < 4; ++r) {
                    float best = 3.4e38f; int bidx = 0x7fffffff;
                    #pragma unroll
                    for (int t = 0; t < 4; ++t) {
                        float sc = esv[t] - 2.f * acc[s][t][r];
                        int k = n0 + w * 64 + t * 16 + fr;
                        if (sc < best || (sc == best && k < bidx)) { best = sc; bidx = k; }
                    }
                    #pragma unroll
                    for (int msk = 1; msk <= 8; msk <<= 1) {
                        float so = __shfl_xor(best, msk, 64);
                        int ko2 = __shfl_xor(bidx, msk, 64);
                        if (so < best || (so == best && ko2 < bidx)) { best = so; bidx = ko2; }
                    }
                    if (fr == 0) {
                        int m = m0 + s * 16 + fq * 4 + r;
                        ps2[(size_t)m * 128 + colIdx] = best;
                        pi2[(size_t)m * 128 + colIdx] = bidx;
                    }
                }
            }
            #pragma unroll
            for (int s = 0; s < 4; ++s)
                #pragma unroll
                for (int t = 0; t < 4; ++t)
                    #pragma unroll
                    for (int r = 0; r < 4; ++r) acc[s][t][r] = 0.f;
        }
    }
}

// ---------------- exact fp32 refine, grid-stride (512 blocks) ----------------
__global__ __launch_bounds__(256) void refine3_k(
    const float* __restrict__ y, const float* __restrict__ emb,
    const float* __restrict__ esq, const float* __restrict__ ps2,
    const int* __restrict__ pi2, int* __restrict__ out) {
    int lane = threadIdx.x & 63;
    for (int j = 0; j < 8; ++j) {
        int m = blockIdx.x * 32 + j * 4 + (threadIdx.x >> 6);
        float4 yv = *(const float4*)(y + (size_t)m * 256 + lane * 4);
        float sc_[2]; int kc_[2];
        #pragma unroll
        for (int i = 0; i < 2; ++i) {
            sc_[i] = ps2[(size_t)m * 128 + lane * 2 + i];
            kc_[i] = pi2[(size_t)m * 128 + lane * 2 + i];
        }
        float s0 = fminf(sc_[0], sc_[1]);
        #pragma unroll
        for (int msk = 1; msk <= 32; msk <<= 1) s0 = fminf(s0, __shfl_xor(s0, msk, 64));
        float thr = s0 + 0.25f;
        float best = 3.4e38f; int bk = 0x7fffffff;
        for (int c = 0; c < 128; ++c) {
            float scc = __shfl(sc_[c & 1], c >> 1, 64);
            if (scc <= thr) {            // wave-uniform
                int k = __shfl(kc_[c & 1], c >> 1, 64);
                float4 ev = *(const float4*)(emb + (size_t)k * 256 + lane * 4);
                float d = yv.x * ev.x + yv.y * ev.y + yv.z * ev.z + yv.w * ev.w;
                #pragma unroll
                for (int msk = 1; msk <= 32; msk <<= 1) d += __shfl_xor(d, msk, 64);
                float sx = esq[k] - 2.f * d;
                if (sx < best || (sx == best && k < bk)) { best = sx; bk = k; }
            }
        }
        if (lane == 0) out[m] = bk;
    }
}

extern "C" void kernel_launch(void* const* d_in, const int* in_sizes, int n_in,
                              void* d_out, int out_size, void* d_ws, size_t ws_size,
                              hipStream_t stream) {
    const float* latent = (const float*)d_in[0];
    const float* conv_w = (const float*)d_in[1];
    const float* conv_b = (const float*)d_in[2];
    const float* lin_w  = (const float*)d_in[3];
    const float* lin_b  = (const float*)d_in[4];
    const float* emb    = (const float*)d_in[5];
    int* out = (int*)d_out;

    char* W = (char*)d_ws;                           // proven 55.35 MB budget
    float*    lwT = (float*)(W + 0);                 //   262,144
    float*    b2  = (float*)(W + 262144);            //     1,024
    float*    esq = (float*)(W + 263168);            //    32,768
    float*    yb  = (float*)(W + 295936);            // 16,777,216
    _Float16* W2x = (_Float16*)(W + 17073152);       //  4,718,592
    _Float16* Xnp = (_Float16*)(W + 21792768);       // 33,554,432 (live: packlat -> convm6)
    // post-conv aliases on the (dead) Xnp region:
    _Float16* A2  = (_Float16*)(W + 21792768);       //  8,388,608 (pack2 -> screen9)
    _Float16* B2  = (_Float16*)(W + 30181376);       //  4,194,304 (pack2 -> screen9)
    float*    ps2 = (float*)(W + 34375680);          //  8,388,608 (screen9 -> refine3)
    int*      pi2 = (int*)(W + 42764288);            //  8,388,608 -> ends 51,152,896

    dim3 t32(32, 32);
    tkern<<<dim3(8, 8), t32, 0, stream>>>(lin_w, lwT, 256, 256);
    bias_k<<<1, 256, 0, stream>>>(lwT, conv_b, lin_b, b2);
    fold5_k<<<576, 256, 0, stream>>>(conv_w, lwT, W2x);
    packlat_k<<<256, 256, 0, stream>>>(latent, Xnp);

    convm6_k<<<dim3(128, 2), 256, 0, stream>>>(Xnp, W2x, b2, yb);

    pack2_k<<<512, 256, 0, stream>>>(yb, emb, A2, B2, esq);   // Xnp dead here
    screen9_k<<<256, 512, 0, stream>>>(A2, B2, esq, ps2, pi2);
    refine3_k<<<512, 256, 0, stream>>>(yb, emb, esq, ps2, pi2, out);
}

// Round 4
// 516.310 us; speedup vs baseline: 1.0799x; 1.0799x over previous
//
#include <hip/hip_runtime.h>
#include <cstdint>
#include <cstddef>

// ============================================================================
// VQ-VAE encode: conv3x3(SAME) -> linear (folded) -> argmin over 8192 codes.
//
// Round 14: screen10_k = barrier-free per-wave pipelined screen.
//   R13 post-mortem: counted-vmcnt on a 2-phase barrier loop is NULL (guide
//   regime-gate); per-barrier-phase wall ~1.9us dominates regardless. Fix:
//   remove ALL main-loop barriers. Wave w's B-slice (codes w*64..+63) is
//   private -> per-wave 4-deep LDS ring (8w x 4 x 4KB) staged and consumed
//   by the same wave; ordering via per-wave FIFO vmcnt only. A (64x256 fp16)
//   lives in registers (af[8][4], 128 VGPR; slot-permute algebra cancels ->
//   identical fragment values). esq staged to LDS once (one prologue
//   barrier). Epilogue stores counted in the vmcnt FIFO: waits are 12
//   steady-state, 44 for 4 chunks after an epilogue (12 loads + 32 stores,
//   in-order decrement per m135), 8/4/0 at tail. sched_barrier(0) after
//   lgkmcnt(0) per chunk (rule #18) so ring overwrite can't pass the reads.
//   LDS 160 KB total (AITER-proven size). Scores bitwise identical to
//   screen7/8/9 (same MFMA order, same fragments); ps2/pi2 format unchanged.
//   convm6_k / pack2_k / refine3_k: unchanged.
// argmin tie-break everywhere: strict < with smaller-index preference.
// ============================================================================

#define CIN_  512
#define E_    4608
#define M_    16384

typedef _Float16 half4_t __attribute__((ext_vector_type(4)));
typedef _Float16 half8_t __attribute__((ext_vector_type(8)));
typedef float f32x4 __attribute__((ext_vector_type(4)));

#define GLOAD_LDS16(gptr, lptr)                                         \
    __builtin_amdgcn_global_load_lds(                                   \
        (const __attribute__((address_space(1))) unsigned int*)(gptr),  \
        (__attribute__((address_space(3))) unsigned int*)(lptr), 16, 0, 0)

#define WAITVM(N) asm volatile("s_waitcnt vmcnt(" #N ")" ::: "memory")

// ---------------- transpose ----------------
__global__ void tkern(const float* __restrict__ src, float* __restrict__ dst,
                      int R, int C) {
    __shared__ float t[32][33];
    int c = blockIdx.x * 32 + threadIdx.x;
    int r = blockIdx.y * 32 + threadIdx.y;
    if (r < R && c < C) t[threadIdx.y][threadIdx.x] = src[(size_t)r * C + c];
    __syncthreads();
    int rr = blockIdx.x * 32 + threadIdx.y;
    int cc = blockIdx.y * 32 + threadIdx.x;
    if (rr < C && cc < R) dst[(size_t)rr * R + cc] = t[threadIdx.x][threadIdx.y];
}

// ---------------- fold: W2x[plane][tap][d][512c] fp16 hi/lo ----------------
__global__ __launch_bounds__(256) void fold5_k(const float* __restrict__ conv_w,
                                               const float* __restrict__ lwT,
                                               _Float16* __restrict__ W2x) {
    int e0 = blockIdx.x * 8;
    int d = threadIdx.x;
    float acc[8];
    #pragma unroll
    for (int j = 0; j < 8; ++j) acc[j] = 0.f;
    for (int co = 0; co < 256; ++co) {
        float lw = lwT[co * 256 + d];
        const float* cwr = conv_w + (size_t)co * E_ + e0;   // wave-uniform
        #pragma unroll
        for (int j = 0; j < 8; ++j) acc[j] += cwr[j] * lw;
    }
    #pragma unroll
    for (int j = 0; j < 8; ++j) {
        int e = e0 + j;
        int c = e / 9, t9 = e - c * 9;
        _Float16 h = (_Float16)acc[j];
        _Float16 l = (_Float16)(acc[j] - (float)h);
        W2x[((size_t)(t9 * 256 + d)) * 512 + c] = h;
        W2x[((size_t)((9 + t9) * 256 + d)) * 512 + c] = l;
    }
}

__global__ void bias_k(const float* __restrict__ lwT, const float* __restrict__ conv_b,
                       const float* __restrict__ lin_b, float* __restrict__ b2) {
    int d = threadIdx.x;
    float acc = lin_b[d];
    for (int co = 0; co < 256; ++co) acc += lwT[co * 256 + d] * conv_b[co];
    b2[d] = acc;
}

// ---------------- latent -> channel-last fp16 hi/lo planes ----------------
__global__ __launch_bounds__(256) void packlat_k(const float* __restrict__ lat,
                                                 _Float16* __restrict__ Xnp) {
    int b = blockIdx.x, t = threadIdx.x;
    __shared__ float lt[128][65];
    const float* src = lat + (size_t)b * 512 * 64;
    _Float16* dst = Xnp + (size_t)b * 64 * 1024;
    for (int c0 = 0; c0 < 512; c0 += 128) {
        __syncthreads();
        #pragma unroll
        for (int j = 0; j < 8; ++j) {
            int f4 = t + j * 256;
            int cc = f4 >> 4, p4 = (f4 & 15) * 4;
            float4 v = *(const float4*)(src + (size_t)(c0 + cc) * 64 + p4);
            lt[cc][p4] = v.x; lt[cc][p4 + 1] = v.y;
            lt[cc][p4 + 2] = v.z; lt[cc][p4 + 3] = v.w;
        }
        __syncthreads();
        int pix = t >> 2, cr = (t & 3) * 32;
        #pragma unroll
        for (int q = 0; q < 4; ++q) {
            half8_t hh, ll;
            #pragma unroll
            for (int j = 0; j < 8; ++j) {
                float v = lt[cr + q * 8 + j][pix];
                _Float16 h = (_Float16)v;
                hh[j] = h; ll[j] = (_Float16)(v - (float)h);
            }
            *(half8_t*)(dst + (size_t)pix * 1024 + c0 + cr + q * 8) = hh;
            *(half8_t*)(dst + (size_t)pix * 1024 + 512 + c0 + cr + q * 8) = ll;
        }
    }
}

// ---------------- conv MFMA v6: in-LDS tap shifts, A staged once per chunk --
// grid (128 m-tiles, 2 n-halves), 256 thr = 4 waves (2x2 of 64x64).
// LDS 64 KB static: A dbuf 2 x {Ah 8K, Al 8K} + B dbuf 2 x {Bh 8K, Bl 8K}.
__global__ __launch_bounds__(256) void convm6_k(
    const _Float16* __restrict__ Xnp, const _Float16* __restrict__ W2x,
    const float* __restrict__ b2, float* __restrict__ yb) {
    __shared__ char sm[65536];
    int m0 = blockIdx.x * 128, n0 = blockIdx.y * 128;
    int tid = threadIdx.x, w = tid >> 6, lane = tid & 63;
    int wm = w & 1, wn = w >> 1;
    int fr = lane & 15, fq = lane >> 4;

    // B fragment-read offsets (convm4-verified slot-permute)
    int xq = (fq ^ ((fr >> 1) & 3)) << 4;
    int boff[4];
    #pragma unroll
    for (int i = 0; i < 4; ++i) boff[i] = (wn * 64 + i * 16 + fr) * 64 + xq;
    // A fragment row geometry: rr = wm*64 + s*16 + fr -> (imgbit, ph, pw)
    int imgoff[4], ph[4], pw[4];
    #pragma unroll
    for (int s = 0; s < 4; ++s) {
        int rr = wm * 64 + s * 16 + fr;
        imgoff[s] = rr & 64; ph[s] = (rr >> 3) & 7; pw[s] = rr & 7;
    }
    // staging slot geometry (2 granules per thread per 8 KB tile)
    int slt[2], sr[2], sq[2];
    #pragma unroll
    for (int i = 0; i < 2; ++i) {
        int s = w * 128 + i * 64 + lane;
        slt[i] = s;
        sr[i] = s >> 2;
        sq[i] = ((s & 3) ^ ((s >> 3) & 3)) * 8;
    }

    auto stageA = [&](int cc, int buf) {
        char* L = sm + buf * 16384;
        #pragma unroll
        for (int i = 0; i < 2; ++i) {
            const _Float16* base =
                Xnp + (size_t)(m0 + sr[i]) * 1024 + cc * 32 + sq[i];
            GLOAD_LDS16(base, L + slt[i] * 16);              // hi plane
            GLOAD_LDS16(base + 512, L + 8192 + slt[i] * 16); // lo plane
        }
    };
    auto stageB = [&](int tap, int cc, int buf) {
        char* L = sm + 32768 + buf * 16384;
        #pragma unroll
        for (int i = 0; i < 2; ++i) {
            const _Float16* bb =
                W2x + ((size_t)(tap * 256 + n0 + sr[i])) * 512 + cc * 32 + sq[i];
            GLOAD_LDS16(bb, L + slt[i] * 16);
            GLOAD_LDS16(bb + (size_t)9 * 256 * 512, L + 8192 + slt[i] * 16);
        }
    };

    f32x4 acc[4][4];
    #pragma unroll
    for (int s = 0; s < 4; ++s)
        #pragma unroll
        for (int t = 0; t < 4; ++t)
            #pragma unroll
            for (int r = 0; r < 4; ++r) acc[s][t][r] = 0.f;

    stageA(0, 0);
    stageB(0, 0, 0);
    const half8_t zfrag = {};
    int gi = 0;
    for (int cc = 0; cc < 16; ++cc) {
        const char* Ab = sm + (cc & 1) * 16384;
        for (int tap = 0; tap < 9; ++tap, ++gi) {
            __syncthreads();
            if (tap < 8) stageB(tap + 1, cc, (gi + 1) & 1);
            else if (cc < 15) stageB(0, cc + 1, (gi + 1) & 1);
            if (tap == 7 && cc < 15) stageA(cc + 1, (cc + 1) & 1);

            int dy = tap / 3 - 1, dx = tap - (tap / 3) * 3 - 1;
            // A fragments: shifted pixels, invalid -> zero
            half8_t ah[4], al[4];
            #pragma unroll
            for (int s = 0; s < 4; ++s) {
                int ih = ph[s] + dy, iw = pw[s] + dx;
                bool v = ((unsigned)ih < 8u) && ((unsigned)iw < 8u);
                int pp = imgoff[s] + (v ? ih * 8 + iw : 0);
                int ao = pp * 64 + ((fq ^ ((pp >> 1) & 3)) << 4);
                half8_t a0 = *(const half8_t*)(Ab + ao);
                half8_t a1 = *(const half8_t*)(Ab + 8192 + ao);
                ah[s] = v ? a0 : zfrag;
                al[s] = v ? a1 : zfrag;
            }
            const char* Bb = sm + 32768 + (gi & 1) * 16384;
            half8_t bh[4], bl[4];
            #pragma unroll
            for (int t = 0; t < 4; ++t) {
                bh[t] = *(const half8_t*)(Bb + boff[t]);
                bl[t] = *(const half8_t*)(Bb + 8192 + boff[t]);
            }
            #pragma unroll
            for (int s = 0; s < 4; ++s)
                #pragma unroll
                for (int t = 0; t < 4; ++t)
                    acc[s][t] = __builtin_amdgcn_mfma_f32_16x16x32_f16(
                        ah[s], bh[t], acc[s][t], 0, 0, 0);
            #pragma unroll
            for (int s = 0; s < 4; ++s)
                #pragma unroll
                for (int t = 0; t < 4; ++t)
                    acc[s][t] = __builtin_amdgcn_mfma_f32_16x16x32_f16(
                        ah[s], bl[t], acc[s][t], 0, 0, 0);
            #pragma unroll
            for (int s = 0; s < 4; ++s)
                #pragma unroll
                for (int t = 0; t < 4; ++t)
                    acc[s][t] = __builtin_amdgcn_mfma_f32_16x16x32_f16(
                        al[s], bh[t], acc[s][t], 0, 0, 0);
        }
    }

    // epilogue: +bias, write yb fp32 only
    float bv[4];
    #pragma unroll
    for (int t = 0; t < 4; ++t) bv[t] = b2[n0 + wn * 64 + t * 16 + fr];
    #pragma unroll
    for (int s = 0; s < 4; ++s)
        #pragma unroll
        for (int r = 0; r < 4; ++r) {
            int m = m0 + wm * 64 + s * 16 + fq * 4 + r;
            #pragma unroll
            for (int t = 0; t < 4; ++t) {
                int d = n0 + wn * 64 + t * 16 + fr;
                yb[(size_t)m * 256 + d] = acc[s][t][r] + bv[t];
            }
        }
}

// ---------------- fused post-conv pack: A2<-yb, B2<-emb, esq<-emb ----------
// 512 blocks x 256 thr. Runs AFTER convm6 (Xnp dead -> A2/B2 regions free).
__global__ __launch_bounds__(256) void pack2_k(
    const float* __restrict__ yb, const float* __restrict__ emb,
    _Float16* __restrict__ A2, _Float16* __restrict__ B2,
    float* __restrict__ esq) {
    // A2 <- yb : 16384 rows x 256 = 1,048,576 float4 groups
    #pragma unroll
    for (int it = 0; it < 8; ++it) {
        int i = (blockIdx.x + it * 512) * 256 + threadIdx.x;
        float4 v = *(const float4*)(yb + (size_t)i * 4);
        half4_t h = {(_Float16)v.x, (_Float16)v.y, (_Float16)v.z, (_Float16)v.w};
        *(half4_t*)(A2 + (size_t)i * 4) = h;
    }
    // B2 + esq <- emb : 8192 rows
    int w = threadIdx.x >> 6, lane = threadIdx.x & 63;
    #pragma unroll
    for (int j = 0; j < 4; ++j) {
        int k = blockIdx.x * 16 + w * 4 + j;
        float4 v = *(const float4*)(emb + (size_t)k * 256 + lane * 4);
        half4_t h = {(_Float16)v.x, (_Float16)v.y, (_Float16)v.z, (_Float16)v.w};
        *(half4_t*)(B2 + (size_t)k * 256 + lane * 4) = h;
        float s = v.x * v.x + v.y * v.y + v.z * v.z + v.w * v.w;
        #pragma unroll
        for (int m = 32; m >= 1; m >>= 1) s += __shfl_xor(s, m, 64);
        if (lane == 0) esq[k] = s;
    }
}

// ---------------- MFMA screen v10: barrier-free per-wave pipeline ----------
// grid 256 (one block per 64-row m-tile), 512 thr = 8 waves. Wave w owns
// codes [nt*512 + w*64, +64) -- its B-slice is wave-private. A in registers
// (af[8][4]); esq in LDS (published by the single prologue barrier). B
// streams through a per-wave 4-deep ring of 4 KB LDS buffers, staged by
// global_load_lds and consumed by the same wave: ordering = per-wave FIFO
// vmcnt + lgkmcnt only, ZERO main-loop barriers. Chunk gi = nt*8+kt;
// chunk gi+4 staged at gi (prefetch depth 3). vmcnt waits: 12 steady;
// 44 for the 4 chunks after an epilogue (12 loads + 32 stores, in-order
// FIFO decrement); 12/8/4/0 at tail. Scores bitwise identical to screen7/8/9.
__global__ __launch_bounds__(512, 2) void screen10_k(
    const _Float16* __restrict__ A2, const _Float16* __restrict__ B2,
    const float* __restrict__ esq, float* __restrict__ ps2, int* __restrict__ pi2) {
    __shared__ char sm[163840];   // 8 waves x 4 bufs x 4 KB | esq 32 KB @131072
    int m0 = blockIdx.x * 64;
    int tid = threadIdx.x, w = tid >> 6, lane = tid & 63;
    int fr = lane & 15, fq = lane >> 4;
    int xq = (fq ^ ((fr >> 1) & 3)) << 4;

    char* smw = sm + w * 16384;                    // this wave's B ring
    const float* esqL = (const float*)(sm + 131072);

    // fragment-read offsets within a 4 KB buffer (proven slot-permute)
    int boffl[4];
    #pragma unroll
    for (int i = 0; i < 4; ++i) boffl[i] = (i * 16 + fr) * 64 + xq;

    // per-lane staging source base: row = w*64 + (lane>>2), quad-permuted col
    int sql = ((lane & 3) ^ ((lane >> 3) & 3)) * 8;
    const _Float16* Bsrc = B2 + (size_t)(w * 64 + (lane >> 2)) * 256 + sql;

    // ---- prologue: A -> registers (natural fragments), esq -> LDS ----
    half8_t af[8][4];
    #pragma unroll
    for (int kt = 0; kt < 8; ++kt)
        #pragma unroll
        for (int s = 0; s < 4; ++s)
            af[kt][s] = *(const half8_t*)(
                A2 + (size_t)(m0 + s * 16 + fr) * 256 + kt * 32 + fq * 8);
    #pragma unroll
    for (int i = 0; i < 4; ++i) {
        int g = i * 512 + tid;
        GLOAD_LDS16(esq + (size_t)g * 4, sm + 131072 + g * 16);
    }
    WAITVM(0);
    __builtin_amdgcn_s_barrier();     // publish esq (the ONLY barrier)

    // stage chunks 0..3 (n-tile 0, ko = c*32) into ring bufs 0..3
    #pragma unroll
    for (int c = 0; c < 4; ++c)
        #pragma unroll
        for (int i = 0; i < 4; ++i)
            GLOAD_LDS16(Bsrc + (size_t)(i * 16) * 256 + c * 32,
                        smw + c * 4096 + i * 1024 + lane * 16);

    f32x4 acc[4][4];
    #pragma unroll
    for (int s = 0; s < 4; ++s)
        #pragma unroll
        for (int t = 0; t < 4; ++t)
            #pragma unroll
            for (int r = 0; r < 4; ++r) acc[s][t][r] = 0.f;

    for (int nt = 0; nt < 16; ++nt) {
        #pragma unroll
        for (int kt = 0; kt < 8; ++kt) {
            // wait for chunk gi = nt*8+kt (FIFO; stores counted in-order)
            if (kt <= 3) {
                if (nt == 0) { WAITVM(12); } else { WAITVM(44); }
            } else if (kt == 4) {
                WAITVM(12);
            } else if (kt == 5) {
                if (nt < 15) { WAITVM(12); } else { WAITVM(8); }
            } else if (kt == 6) {
                if (nt < 15) { WAITVM(12); } else { WAITVM(4); }
            } else {
                if (nt < 15) { WAITVM(12); } else { WAITVM(0); }
            }

            const char* Bb = smw + (kt & 3) * 4096;
            half8_t bf[4];
            #pragma unroll
            for (int t = 0; t < 4; ++t) bf[t] = *(const half8_t*)(Bb + boffl[t]);
            asm volatile("s_waitcnt lgkmcnt(0)" ::: "memory");
            __builtin_amdgcn_sched_barrier(0);   // reads done before overwrite

            // stage chunk gi+4 into the buffer just consumed (same wave)
            if (nt < 15 || kt < 4) {
                int cn0 = nt * 512 + ((kt >= 4) ? 512 : 0);
                int cko = ((kt + 4) & 7) * 32;
                const _Float16* src = Bsrc + (size_t)cn0 * 256 + cko;
                char* Ld = smw + (kt & 3) * 4096;
                #pragma unroll
                for (int i = 0; i < 4; ++i)
                    GLOAD_LDS16(src + (size_t)(i * 16) * 256,
                                Ld + i * 1024 + lane * 16);
            }

            __builtin_amdgcn_s_setprio(1);
            #pragma unroll
            for (int s = 0; s < 4; ++s)
                #pragma unroll
                for (int t = 0; t < 4; ++t)
                    acc[s][t] = __builtin_amdgcn_mfma_f32_16x16x32_f16(
                        af[kt][s], bf[t], acc[s][t], 0, 0, 0);
            __builtin_amdgcn_s_setprio(0);
        }

        // ---- per-n-tile argmin epilogue (esq from LDS; 32 global stores) ----
        int n0 = nt * 512;
        float esv[4];
        #pragma unroll
        for (int t = 0; t < 4; ++t) esv[t] = esqL[n0 + w * 64 + t * 16 + fr];
        int colIdx = nt * 8 + w;
        #pragma unroll
        for (int s = 0; s < 4; ++s) {
            #pragma unroll
            for (int r = 0; r < 4; ++r) {
                float best = 3.4e38f; int bidx = 0x7fffffff;
                #pragma unroll
                for (int t = 0; t < 4; ++t) {
                    float sc = esv[t] - 2.f * acc[s][t][r];
                    int k = n0 + w * 64 + t * 16 + fr;
                    if (sc < best || (sc == best && k < bidx)) { best = sc; bidx = k; }
                }
                #pragma unroll
                for (int msk = 1; msk <= 8; msk <<= 1) {
                    float so = __shfl_xor(best, msk, 64);
                    int ko2 = __shfl_xor(bidx, msk, 64);
                    if (so < best || (so == best && ko2 < bidx)) { best = so; bidx = ko2; }
                }
                if (fr == 0) {
                    int m = m0 + s * 16 + fq * 4 + r;
                    ps2[(size_t)m * 128 + colIdx] = best;
                    pi2[(size_t)m * 128 + colIdx] = bidx;
                }
            }
        }
        #pragma unroll
        for (int s = 0; s < 4; ++s)
            #pragma unroll
            for (int t = 0; t < 4; ++t)
                #pragma unroll
                for (int r = 0; r < 4; ++r) acc[s][t][r] = 0.f;
    }
}

// ---------------- exact fp32 refine, grid-stride (512 blocks) ----------------
__global__ __launch_bounds__(256) void refine3_k(
    const float* __restrict__ y, const float* __restrict__ emb,
    const float* __restrict__ esq, const float* __restrict__ ps2,
    const int* __restrict__ pi2, int* __restrict__ out) {
    int lane = threadIdx.x & 63;
    for (int j = 0; j < 8; ++j) {
        int m = blockIdx.x * 32 + j * 4 + (threadIdx.x >> 6);
        float4 yv = *(const float4*)(y + (size_t)m * 256 + lane * 4);
        float sc_[2]; int kc_[2];
        #pragma unroll
        for (int i = 0; i < 2; ++i) {
            sc_[i] = ps2[(size_t)m * 128 + lane * 2 + i];
            kc_[i] = pi2[(size_t)m * 128 + lane * 2 + i];
        }
        float s0 = fminf(sc_[0], sc_[1]);
        #pragma unroll
        for (int msk = 1; msk <= 32; msk <<= 1) s0 = fminf(s0, __shfl_xor(s0, msk, 64));
        float thr = s0 + 0.25f;
        float best = 3.4e38f; int bk = 0x7fffffff;
        for (int c = 0; c < 128; ++c) {
            float scc = __shfl(sc_[c & 1], c >> 1, 64);
            if (scc <= thr) {            // wave-uniform
                int k = __shfl(kc_[c & 1], c >> 1, 64);
                float4 ev = *(const float4*)(emb + (size_t)k * 256 + lane * 4);
                float d = yv.x * ev.x + yv.y * ev.y + yv.z * ev.z + yv.w * ev.w;
                #pragma unroll
                for (int msk = 1; msk <= 32; msk <<= 1) d += __shfl_xor(d, msk, 64);
                float sx = esq[k] - 2.f * d;
                if (sx < best || (sx == best && k < bk)) { best = sx; bk = k; }
            }
        }
        if (lane == 0) out[m] = bk;
    }
}

extern "C" void kernel_launch(void* const* d_in, const int* in_sizes, int n_in,
                              void* d_out, int out_size, void* d_ws, size_t ws_size,
                              hipStream_t stream) {
    const float* latent = (const float*)d_in[0];
    const float* conv_w = (const float*)d_in[1];
    const float* conv_b = (const float*)d_in[2];
    const float* lin_w  = (const float*)d_in[3];
    const float* lin_b  = (const float*)d_in[4];
    const float* emb    = (const float*)d_in[5];
    int* out = (int*)d_out;

    char* W = (char*)d_ws;                           // proven 55.35 MB budget
    float*    lwT = (float*)(W + 0);                 //   262,144
    float*    b2  = (float*)(W + 262144);            //     1,024
    float*    esq = (float*)(W + 263168);            //    32,768
    float*    yb  = (float*)(W + 295936);            // 16,777,216
    _Float16* W2x = (_Float16*)(W + 17073152);       //  4,718,592
    _Float16* Xnp = (_Float16*)(W + 21792768);       // 33,554,432 (live: packlat -> convm6)
    // post-conv aliases on the (dead) Xnp region:
    _Float16* A2  = (_Float16*)(W + 21792768);       //  8,388,608 (pack2 -> screen10)
    _Float16* B2  = (_Float16*)(W + 30181376);       //  4,194,304 (pack2 -> screen10)
    float*    ps2 = (float*)(W + 34375680);          //  8,388,608 (screen10 -> refine3)
    int*      pi2 = (int*)(W + 42764288);            //  8,388,608 -> ends 51,152,896

    dim3 t32(32, 32);
    tkern<<<dim3(8, 8), t32, 0, stream>>>(lin_w, lwT, 256, 256);
    bias_k<<<1, 256, 0, stream>>>(lwT, conv_b, lin_b, b2);
    fold5_k<<<576, 256, 0, stream>>>(conv_w, lwT, W2x);
    packlat_k<<<256, 256, 0, stream>>>(latent, Xnp);

    convm6_k<<<dim3(128, 2), 256, 0, stream>>>(Xnp, W2x, b2, yb);

    pack2_k<<<512, 256, 0, stream>>>(yb, emb, A2, B2, esq);   // Xnp dead here
    screen10_k<<<256, 512, 0, stream>>>(A2, B2, esq, ps2, pi2);
    refine3_k<<<512, 256, 0, stream>>>(yb, emb, esq, ps2, pi2, out);
}

// Round 5
// 453.179 us; speedup vs baseline: 1.2303x; 1.1393x over previous
//
#include <hip/hip_runtime.h>
#include <cstdint>
#include <cstddef>

// ============================================================================
// VQ-VAE encode: conv3x3(SAME) -> linear (folded) -> argmin over 8192 codes.
//
// Round 15: screen11_k = screen7's PROVEN structure, widened to 128x256.
//   R12-R14 post-mortem: three screen rewrites (1 block/CU: counted-vmcnt,
//   barrier-free per-wave rings) all landed 211-245us vs screen7's 166us.
//   Lesson: block-level TLP (multi-block co-residency) is the only latency
//   hiding that works here; in-block pipelining does not pay. So: keep
//   screen7's 2-phase __syncthreads loop + co-residency, improve economics:
//   tile 128x256 (512thr, 8 waves, each the proven 64x64). Blocks/CU 32->16
//   (epilogue count halves), staging per unit work drops 1.5x (LDS floor
//   ~68->~40us), LDS 48KB -> 3 blocks/CU resident (>= screen7's 2.6).
//   Slot-permute formulas re-derived: XOR term (row>>1)&3 == (fr>>1)&3 for
//   all wave offsets (multiples of 16/64). Per-element MFMA sequence
//   unchanged -> scores bitwise identical; ps2/pi2 contract unchanged
//   (colIdx = nt*4 + wn; refine3 uses stored k's only).
//   convm6 untouched (unmeasured, bounded <=166us; surfaces in top-5 next
//   round if it becomes the max -- then attack with data).
// argmin tie-break everywhere: strict < with smaller-index preference.
// ============================================================================

#define CIN_  512
#define E_    4608
#define M_    16384

typedef _Float16 half4_t __attribute__((ext_vector_type(4)));
typedef _Float16 half8_t __attribute__((ext_vector_type(8)));
typedef float f32x4 __attribute__((ext_vector_type(4)));

#define GLOAD_LDS16(gptr, lptr)                                         \
    __builtin_amdgcn_global_load_lds(                                   \
        (const __attribute__((address_space(1))) unsigned int*)(gptr),  \
        (__attribute__((address_space(3))) unsigned int*)(lptr), 16, 0, 0)

// ---------------- transpose ----------------
__global__ void tkern(const float* __restrict__ src, float* __restrict__ dst,
                      int R, int C) {
    __shared__ float t[32][33];
    int c = blockIdx.x * 32 + threadIdx.x;
    int r = blockIdx.y * 32 + threadIdx.y;
    if (r < R && c < C) t[threadIdx.y][threadIdx.x] = src[(size_t)r * C + c];
    __syncthreads();
    int rr = blockIdx.x * 32 + threadIdx.y;
    int cc = blockIdx.y * 32 + threadIdx.x;
    if (rr < C && cc < R) dst[(size_t)rr * R + cc] = t[threadIdx.x][threadIdx.y];
}

// ---------------- fold: W2x[plane][tap][d][512c] fp16 hi/lo ----------------
__global__ __launch_bounds__(256) void fold5_k(const float* __restrict__ conv_w,
                                               const float* __restrict__ lwT,
                                               _Float16* __restrict__ W2x) {
    int e0 = blockIdx.x * 8;
    int d = threadIdx.x;
    float acc[8];
    #pragma unroll
    for (int j = 0; j < 8; ++j) acc[j] = 0.f;
    for (int co = 0; co < 256; ++co) {
        float lw = lwT[co * 256 + d];
        const float* cwr = conv_w + (size_t)co * E_ + e0;   // wave-uniform
        #pragma unroll
        for (int j = 0; j < 8; ++j) acc[j] += cwr[j] * lw;
    }
    #pragma unroll
    for (int j = 0; j < 8; ++j) {
        int e = e0 + j;
        int c = e / 9, t9 = e - c * 9;
        _Float16 h = (_Float16)acc[j];
        _Float16 l = (_Float16)(acc[j] - (float)h);
        W2x[((size_t)(t9 * 256 + d)) * 512 + c] = h;
        W2x[((size_t)((9 + t9) * 256 + d)) * 512 + c] = l;
    }
}

__global__ void bias_k(const float* __restrict__ lwT, const float* __restrict__ conv_b,
                       const float* __restrict__ lin_b, float* __restrict__ b2) {
    int d = threadIdx.x;
    float acc = lin_b[d];
    for (int co = 0; co < 256; ++co) acc += lwT[co * 256 + d] * conv_b[co];
    b2[d] = acc;
}

// ---------------- latent -> channel-last fp16 hi/lo planes ----------------
__global__ __launch_bounds__(256) void packlat_k(const float* __restrict__ lat,
                                                 _Float16* __restrict__ Xnp) {
    int b = blockIdx.x, t = threadIdx.x;
    __shared__ float lt[128][65];
    const float* src = lat + (size_t)b * 512 * 64;
    _Float16* dst = Xnp + (size_t)b * 64 * 1024;
    for (int c0 = 0; c0 < 512; c0 += 128) {
        __syncthreads();
        #pragma unroll
        for (int j = 0; j < 8; ++j) {
            int f4 = t + j * 256;
            int cc = f4 >> 4, p4 = (f4 & 15) * 4;
            float4 v = *(const float4*)(src + (size_t)(c0 + cc) * 64 + p4);
            lt[cc][p4] = v.x; lt[cc][p4 + 1] = v.y;
            lt[cc][p4 + 2] = v.z; lt[cc][p4 + 3] = v.w;
        }
        __syncthreads();
        int pix = t >> 2, cr = (t & 3) * 32;
        #pragma unroll
        for (int q = 0; q < 4; ++q) {
            half8_t hh, ll;
            #pragma unroll
            for (int j = 0; j < 8; ++j) {
                float v = lt[cr + q * 8 + j][pix];
                _Float16 h = (_Float16)v;
                hh[j] = h; ll[j] = (_Float16)(v - (float)h);
            }
            *(half8_t*)(dst + (size_t)pix * 1024 + c0 + cr + q * 8) = hh;
            *(half8_t*)(dst + (size_t)pix * 1024 + 512 + c0 + cr + q * 8) = ll;
        }
    }
}

// ---------------- conv MFMA v6: in-LDS tap shifts, A staged once per chunk --
// grid (128 m-tiles, 2 n-halves), 256 thr = 4 waves (2x2 of 64x64).
// LDS 64 KB static: A dbuf 2 x {Ah 8K, Al 8K} + B dbuf 2 x {Bh 8K, Bl 8K}.
__global__ __launch_bounds__(256) void convm6_k(
    const _Float16* __restrict__ Xnp, const _Float16* __restrict__ W2x,
    const float* __restrict__ b2, float* __restrict__ yb) {
    __shared__ char sm[65536];
    int m0 = blockIdx.x * 128, n0 = blockIdx.y * 128;
    int tid = threadIdx.x, w = tid >> 6, lane = tid & 63;
    int wm = w & 1, wn = w >> 1;
    int fr = lane & 15, fq = lane >> 4;

    // B fragment-read offsets (convm4-verified slot-permute)
    int xq = (fq ^ ((fr >> 1) & 3)) << 4;
    int boff[4];
    #pragma unroll
    for (int i = 0; i < 4; ++i) boff[i] = (wn * 64 + i * 16 + fr) * 64 + xq;
    // A fragment row geometry: rr = wm*64 + s*16 + fr -> (imgbit, ph, pw)
    int imgoff[4], ph[4], pw[4];
    #pragma unroll
    for (int s = 0; s < 4; ++s) {
        int rr = wm * 64 + s * 16 + fr;
        imgoff[s] = rr & 64; ph[s] = (rr >> 3) & 7; pw[s] = rr & 7;
    }
    // staging slot geometry (2 granules per thread per 8 KB tile)
    int slt[2], sr[2], sq[2];
    #pragma unroll
    for (int i = 0; i < 2; ++i) {
        int s = w * 128 + i * 64 + lane;
        slt[i] = s;
        sr[i] = s >> 2;
        sq[i] = ((s & 3) ^ ((s >> 3) & 3)) * 8;
    }

    auto stageA = [&](int cc, int buf) {
        char* L = sm + buf * 16384;
        #pragma unroll
        for (int i = 0; i < 2; ++i) {
            const _Float16* base =
                Xnp + (size_t)(m0 + sr[i]) * 1024 + cc * 32 + sq[i];
            GLOAD_LDS16(base, L + slt[i] * 16);              // hi plane
            GLOAD_LDS16(base + 512, L + 8192 + slt[i] * 16); // lo plane
        }
    };
    auto stageB = [&](int tap, int cc, int buf) {
        char* L = sm + 32768 + buf * 16384;
        #pragma unroll
        for (int i = 0; i < 2; ++i) {
            const _Float16* bb =
                W2x + ((size_t)(tap * 256 + n0 + sr[i])) * 512 + cc * 32 + sq[i];
            GLOAD_LDS16(bb, L + slt[i] * 16);
            GLOAD_LDS16(bb + (size_t)9 * 256 * 512, L + 8192 + slt[i] * 16);
        }
    };

    f32x4 acc[4][4];
    #pragma unroll
    for (int s = 0; s < 4; ++s)
        #pragma unroll
        for (int t = 0; t < 4; ++t)
            #pragma unroll
            for (int r = 0; r < 4; ++r) acc[s][t][r] = 0.f;

    stageA(0, 0);
    stageB(0, 0, 0);
    const half8_t zfrag = {};
    int gi = 0;
    for (int cc = 0; cc < 16; ++cc) {
        const char* Ab = sm + (cc & 1) * 16384;
        for (int tap = 0; tap < 9; ++tap, ++gi) {
            __syncthreads();
            if (tap < 8) stageB(tap + 1, cc, (gi + 1) & 1);
            else if (cc < 15) stageB(0, cc + 1, (gi + 1) & 1);
            if (tap == 7 && cc < 15) stageA(cc + 1, (cc + 1) & 1);

            int dy = tap / 3 - 1, dx = tap - (tap / 3) * 3 - 1;
            // A fragments: shifted pixels, invalid -> zero
            half8_t ah[4], al[4];
            #pragma unroll
            for (int s = 0; s < 4; ++s) {
                int ih = ph[s] + dy, iw = pw[s] + dx;
                bool v = ((unsigned)ih < 8u) && ((unsigned)iw < 8u);
                int pp = imgoff[s] + (v ? ih * 8 + iw : 0);
                int ao = pp * 64 + ((fq ^ ((pp >> 1) & 3)) << 4);
                half8_t a0 = *(const half8_t*)(Ab + ao);
                half8_t a1 = *(const half8_t*)(Ab + 8192 + ao);
                ah[s] = v ? a0 : zfrag;
                al[s] = v ? a1 : zfrag;
            }
            const char* Bb = sm + 32768 + (gi & 1) * 16384;
            half8_t bh[4], bl[4];
            #pragma unroll
            for (int t = 0; t < 4; ++t) {
                bh[t] = *(const half8_t*)(Bb + boff[t]);
                bl[t] = *(const half8_t*)(Bb + 8192 + boff[t]);
            }
            #pragma unroll
            for (int s = 0; s < 4; ++s)
                #pragma unroll
                for (int t = 0; t < 4; ++t)
                    acc[s][t] = __builtin_amdgcn_mfma_f32_16x16x32_f16(
                        ah[s], bh[t], acc[s][t], 0, 0, 0);
            #pragma unroll
            for (int s = 0; s < 4; ++s)
                #pragma unroll
                for (int t = 0; t < 4; ++t)
                    acc[s][t] = __builtin_amdgcn_mfma_f32_16x16x32_f16(
                        ah[s], bl[t], acc[s][t], 0, 0, 0);
            #pragma unroll
            for (int s = 0; s < 4; ++s)
                #pragma unroll
                for (int t = 0; t < 4; ++t)
                    acc[s][t] = __builtin_amdgcn_mfma_f32_16x16x32_f16(
                        al[s], bh[t], acc[s][t], 0, 0, 0);
        }
    }

    // epilogue: +bias, write yb fp32 only
    float bv[4];
    #pragma unroll
    for (int t = 0; t < 4; ++t) bv[t] = b2[n0 + wn * 64 + t * 16 + fr];
    #pragma unroll
    for (int s = 0; s < 4; ++s)
        #pragma unroll
        for (int r = 0; r < 4; ++r) {
            int m = m0 + wm * 64 + s * 16 + fq * 4 + r;
            #pragma unroll
            for (int t = 0; t < 4; ++t) {
                int d = n0 + wn * 64 + t * 16 + fr;
                yb[(size_t)m * 256 + d] = acc[s][t][r] + bv[t];
            }
        }
}

// ---------------- fused post-conv pack: A2<-yb, B2<-emb, esq<-emb ----------
// 512 blocks x 256 thr. Runs AFTER convm6 (Xnp dead -> A2/B2 regions free).
__global__ __launch_bounds__(256) void pack2_k(
    const float* __restrict__ yb, const float* __restrict__ emb,
    _Float16* __restrict__ A2, _Float16* __restrict__ B2,
    float* __restrict__ esq) {
    // A2 <- yb : 16384 rows x 256 = 1,048,576 float4 groups
    #pragma unroll
    for (int it = 0; it < 8; ++it) {
        int i = (blockIdx.x + it * 512) * 256 + threadIdx.x;
        float4 v = *(const float4*)(yb + (size_t)i * 4);
        half4_t h = {(_Float16)v.x, (_Float16)v.y, (_Float16)v.z, (_Float16)v.w};
        *(half4_t*)(A2 + (size_t)i * 4) = h;
    }
    // B2 + esq <- emb : 8192 rows
    int w = threadIdx.x >> 6, lane = threadIdx.x & 63;
    #pragma unroll
    for (int j = 0; j < 4; ++j) {
        int k = blockIdx.x * 16 + w * 4 + j;
        float4 v = *(const float4*)(emb + (size_t)k * 256 + lane * 4);
        half4_t h = {(_Float16)v.x, (_Float16)v.y, (_Float16)v.z, (_Float16)v.w};
        *(half4_t*)(B2 + (size_t)k * 256 + lane * 4) = h;
        float s = v.x * v.x + v.y * v.y + v.z * v.z + v.w * v.w;
        #pragma unroll
        for (int m = 32; m >= 1; m >>= 1) s += __shfl_xor(s, m, 64);
        if (lane == 0) esq[k] = s;
    }
}

// ---------------- MFMA screen v11: screen7 structure, 128x256 tile ---------
// 1-D grid 4096, 512 thr = 8 waves (2 wm x 4 wn of 64x64). XCD-aware remap:
// xcd = Lb&7 owns m-tiles [xcd*16,+16); j = Lb>>3: mt = xcd*16 + (j&15),
// nt = j>>4 (0..31). LDS 48 KB = dbuf 2 x {A 8K | B 16K} -> 3 blocks/CU.
// Proven 2-phase __syncthreads loop (co-residency hides phase walls).
// colIdx = nt*4 + wn (still one 64-code group per column). Scores bitwise
// identical to screen7 (same per-element MFMA sequence).
__global__ __launch_bounds__(512) void screen11_k(
    const _Float16* __restrict__ A2, const _Float16* __restrict__ B2,
    const float* __restrict__ esq, float* __restrict__ ps2, int* __restrict__ pi2) {
    __shared__ char sm[49152];
    int Lb = blockIdx.x;
    int xcd = Lb & 7, j = Lb >> 3;
    int mt = xcd * 16 + (j & 15);
    int nt = j >> 4;
    int m0 = mt * 128, n0 = nt * 256;
    int tid = threadIdx.x, w = tid >> 6, lane = tid & 63;
    int wm = w & 1, wn = w >> 1;
    int fr = lane & 15, fq = lane >> 4;

    int xq = (fq ^ ((fr >> 1) & 3)) << 4;
    int aoff[4], boff[4];
    #pragma unroll
    for (int i = 0; i < 4; ++i) {
        aoff[i] = (wm * 64 + i * 16 + fr) * 64 + xq;
        boff[i] = (wn * 64 + i * 16 + fr) * 64 + xq;
    }
    // staging: per buffer A 8K (512 granules, 1/thread) + B 16K (1024, 2/thr)
    int sAr = tid >> 2, sAq = ((tid & 3) ^ ((tid >> 3) & 3)) * 8;
    int sBs[2], sBr[2], sBq[2];
    #pragma unroll
    for (int i = 0; i < 2; ++i) {
        int s = i * 512 + tid;
        sBs[i] = s;
        sBr[i] = s >> 2;
        sBq[i] = ((s & 3) ^ ((s >> 3) & 3)) * 8;
    }

    auto stage = [&](int kt, int buf) {
        char* L = sm + buf * 24576;
        int ko = kt * 32;
        GLOAD_LDS16(A2 + (size_t)(m0 + sAr) * 256 + ko + sAq, L + tid * 16);
        #pragma unroll
        for (int i = 0; i < 2; ++i)
            GLOAD_LDS16(B2 + (size_t)(n0 + sBr[i]) * 256 + ko + sBq[i],
                        L + 8192 + sBs[i] * 16);
    };

    f32x4 acc[4][4];
    #pragma unroll
    for (int s = 0; s < 4; ++s)
        #pragma unroll
        for (int t = 0; t < 4; ++t)
            #pragma unroll
            for (int r = 0; r < 4; ++r) acc[s][t][r] = 0.f;

    stage(0, 0);
    for (int kt = 0; kt < 8; ++kt) {
        __syncthreads();
        if (kt + 1 < 8) stage(kt + 1, (kt + 1) & 1);
        const char* L = sm + (kt & 1) * 24576;
        half8_t af[4], bf[4];
        #pragma unroll
        for (int s = 0; s < 4; ++s) af[s] = *(const half8_t*)(L + aoff[s]);
        #pragma unroll
        for (int t = 0; t < 4; ++t) bf[t] = *(const half8_t*)(L + 8192 + boff[t]);
        #pragma unroll
        for (int s = 0; s < 4; ++s)
            #pragma unroll
            for (int t = 0; t < 4; ++t)
                acc[s][t] = __builtin_amdgcn_mfma_f32_16x16x32_f16(
                    af[s], bf[t], acc[s][t], 0, 0, 0);
    }

    float esv[4];
    #pragma unroll
    for (int t = 0; t < 4; ++t) esv[t] = esq[n0 + wn * 64 + t * 16 + fr];
    int colIdx = nt * 4 + wn;
    #pragma unroll
    for (int s = 0; s < 4; ++s) {
        #pragma unroll
        for (int r = 0; r < 4; ++r) {
            float best = 3.4e38f; int bidx = 0x7fffffff;
            #pragma unroll
            for (int t = 0; t < 4; ++t) {
                float sc = esv[t] - 2.f * acc[s][t][r];
                int k = n0 + wn * 64 + t * 16 + fr;
                if (sc < best || (sc == best && k < bidx)) { best = sc; bidx = k; }
            }
            #pragma unroll
            for (int msk = 1; msk <= 8; msk <<= 1) {
                float so = __shfl_xor(best, msk, 64);
                int ko2 = __shfl_xor(bidx, msk, 64);
                if (so < best || (so == best && ko2 < bidx)) { best = so; bidx = ko2; }
            }
            if (fr == 0) {
                int m = m0 + wm * 64 + s * 16 + fq * 4 + r;
                ps2[(size_t)m * 128 + colIdx] = best;
                pi2[(size_t)m * 128 + colIdx] = bidx;
            }
        }
    }
}

// ---------------- exact fp32 refine, grid-stride (512 blocks) ----------------
__global__ __launch_bounds__(256) void refine3_k(
    const float* __restrict__ y, const float* __restrict__ emb,
    const float* __restrict__ esq, const float* __restrict__ ps2,
    const int* __restrict__ pi2, int* __restrict__ out) {
    int lane = threadIdx.x & 63;
    for (int j = 0; j < 8; ++j) {
        int m = blockIdx.x * 32 + j * 4 + (threadIdx.x >> 6);
        float4 yv = *(const float4*)(y + (size_t)m * 256 + lane * 4);
        float sc_[2]; int kc_[2];
        #pragma unroll
        for (int i = 0; i < 2; ++i) {
            sc_[i] = ps2[(size_t)m * 128 + lane * 2 + i];
            kc_[i] = pi2[(size_t)m * 128 + lane * 2 + i];
        }
        float s0 = fminf(sc_[0], sc_[1]);
        #pragma unroll
        for (int msk = 1; msk <= 32; msk <<= 1) s0 = fminf(s0, __shfl_xor(s0, msk, 64));
        float thr = s0 + 0.25f;
        float best = 3.4e38f; int bk = 0x7fffffff;
        for (int c = 0; c < 128; ++c) {
            float scc = __shfl(sc_[c & 1], c >> 1, 64);
            if (scc <= thr) {            // wave-uniform
                int k = __shfl(kc_[c & 1], c >> 1, 64);
                float4 ev = *(const float4*)(emb + (size_t)k * 256 + lane * 4);
                float d = yv.x * ev.x + yv.y * ev.y + yv.z * ev.z + yv.w * ev.w;
                #pragma unroll
                for (int msk = 1; msk <= 32; msk <<= 1) d += __shfl_xor(d, msk, 64);
                float sx = esq[k] - 2.f * d;
                if (sx < best || (sx == best && k < bk)) { best = sx; bk = k; }
            }
        }
        if (lane == 0) out[m] = bk;
    }
}

extern "C" void kernel_launch(void* const* d_in, const int* in_sizes, int n_in,
                              void* d_out, int out_size, void* d_ws, size_t ws_size,
                              hipStream_t stream) {
    const float* latent = (const float*)d_in[0];
    const float* conv_w = (const float*)d_in[1];
    const float* conv_b = (const float*)d_in[2];
    const float* lin_w  = (const float*)d_in[3];
    const float* lin_b  = (const float*)d_in[4];
    const float* emb    = (const float*)d_in[5];
    int* out = (int*)d_out;

    char* W = (char*)d_ws;                           // proven 55.35 MB budget
    float*    lwT = (float*)(W + 0);                 //   262,144
    float*    b2  = (float*)(W + 262144);            //     1,024
    float*    esq = (float*)(W + 263168);            //    32,768
    float*    yb  = (float*)(W + 295936);            // 16,777,216
    _Float16* W2x = (_Float16*)(W + 17073152);       //  4,718,592
    _Float16* Xnp = (_Float16*)(W + 21792768);       // 33,554,432 (live: packlat -> convm6)
    // post-conv aliases on the (dead) Xnp region:
    _Float16* A2  = (_Float16*)(W + 21792768);       //  8,388,608 (pack2 -> screen11)
    _Float16* B2  = (_Float16*)(W + 30181376);       //  4,194,304 (pack2 -> screen11)
    float*    ps2 = (float*)(W + 34375680);          //  8,388,608 (screen11 -> refine3)
    int*      pi2 = (int*)(W + 42764288);            //  8,388,608 -> ends 51,152,896

    dim3 t32(32, 32);
    tkern<<<dim3(8, 8), t32, 0, stream>>>(lin_w, lwT, 256, 256);
    bias_k<<<1, 256, 0, stream>>>(lwT, conv_b, lin_b, b2);
    fold5_k<<<576, 256, 0, stream>>>(conv_w, lwT, W2x);
    packlat_k<<<256, 256, 0, stream>>>(latent, Xnp);

    convm6_k<<<dim3(128, 2), 256, 0, stream>>>(Xnp, W2x, b2, yb);

    pack2_k<<<512, 256, 0, stream>>>(yb, emb, A2, B2, esq);   // Xnp dead here
    screen11_k<<<4096, 512, 0, stream>>>(A2, B2, esq, ps2, pi2);
    refine3_k<<<512, 256, 0, stream>>>(yb, emb, esq, ps2, pi2, out);
}